// Round 2
// baseline (2167.338 us; speedup 1.0000x reference)
//
#include <hip/hip_runtime.h>
#include <stdint.h>

#define D_DIM 128
#define P_DIM 64

// ---- workspace layout (bytes) ----
#define O_CNTR   0x000000ull   // N int
#define O_CNTC   0x080000ull   // N int
#define O_DIS    0x100000ull   // N float
#define O_ROWPTR 0x180000ull   // N+1 int
#define O_CURSOR 0x200000ull   // N int
#define O_PART   0x280000ull   // scan partials
#define O_KT     0x290000ull   // 21*64 float
#define O_MAXW   0x2A0000ull   // 1 uint
#define O_PNT    0x2B0000ull   // 128*64 float (pn transposed)
#define O_U      0x300000ull   // N float
#define O_CSRC   0x400000ull   // E int    (dead after k_struct)
#define O_CSRW   0x1040000ull  // E float  (dead after k_struct)
#define O_XF     0x400000ull   // N*64 uint (bf16x2) -- aliases csr (liveness-disjoint)
#define O_K      0x1C80000ull  // N*64 float

__device__ __forceinline__ float wsumf(float v){
  #pragma unroll
  for (int d=1; d<64; d<<=1) v += __shfl_xor(v, d);
  return v;
}

__device__ __forceinline__ unsigned f2bf(float f){
  unsigned u = __float_as_uint(f);
  return (u + 0x7fffu + ((u>>16)&1u)) >> 16;
}

__device__ __forceinline__ float dp2(unsigned a, unsigned b){
  float al = __uint_as_float(a<<16),  ah = __uint_as_float(a & 0xffff0000u);
  float bl = __uint_as_float(b<<16),  bh = __uint_as_float(b & 0xffff0000u);
  return al*bl + ah*bh;
}

// ---------------- setup kernels ----------------
__global__ void k_zero(int* cntr, int* cntc, float* kt, unsigned* maxw, float* loss_slot, int n){
  int i = blockIdx.x*blockDim.x + threadIdx.x;
  int st = gridDim.x*blockDim.x;
  for (int j=i; j<n; j+=st){ cntr[j]=0; cntc[j]=0; }
  for (int j=i; j<21*64; j+=st) kt[j]=0.f;
  if (i==0){ *maxw = 0u; *loss_slot = 0.f; }
}

__global__ void k_deg(const int* __restrict__ ei, int E, int* cntr, int* cntc){
  int i = blockIdx.x*blockDim.x + threadIdx.x;
  int st = gridDim.x*blockDim.x;
  for (int e=i; e<E; e+=st){
    atomicAdd(&cntr[ei[e]], 1);
    atomicAdd(&cntc[ei[E+e]], 1);
  }
}

__global__ void k_deginv(const int* __restrict__ cntc, float* __restrict__ dis, int n){
  int i = blockIdx.x*blockDim.x + threadIdx.x;
  if (i < n){
    int c = cntc[i];
    dis[i] = (c > 0) ? rsqrtf((float)c) : 0.f;
  }
}

__global__ void k_scan_a(const int* __restrict__ cnt, int* __restrict__ part, int n){
  __shared__ int sm[4];
  int base = blockIdx.x*1024;
  int t = threadIdx.x;
  int s = 0;
  #pragma unroll
  for (int k=0;k<4;k++){ int idx = base + t + 256*k; if (idx<n) s += cnt[idx]; }
  #pragma unroll
  for (int d=1; d<64; d<<=1) s += __shfl_xor(s, d);
  if ((t&63)==0) sm[t>>6] = s;
  __syncthreads();
  if (t==0) part[blockIdx.x] = sm[0]+sm[1]+sm[2]+sm[3];
}

__global__ void k_scan_b(int* part, int nb, int* row_ptr, int n, int E){
  if (threadIdx.x==0 && blockIdx.x==0){
    int run = 0;
    for (int i=0;i<nb;i++){ int v = part[i]; part[i] = run; run += v; }
    row_ptr[n] = E;
  }
}

__global__ void k_scan_c(const int* __restrict__ cnt, const int* __restrict__ part,
                         int* __restrict__ row_ptr, int* __restrict__ cursor, int n){
  __shared__ int warp_tot[4];
  int base = blockIdx.x*1024;
  int t = threadIdx.x;
  int lane = t&63, wv = t>>6;
  int v[4];
  #pragma unroll
  for (int k=0;k<4;k++){ int idx = base + t*4 + k; v[k] = (idx<n) ? cnt[idx] : 0; }
  int local = v[0]+v[1]+v[2]+v[3];
  int sc = local;
  #pragma unroll
  for (int d=1; d<64; d<<=1){ int y = __shfl_up(sc, d); if (lane>=d) sc += y; }
  if (lane==63) warp_tot[wv] = sc;
  __syncthreads();
  int woff = 0;
  for (int i=0;i<wv;i++) woff += warp_tot[i];
  int run = part[blockIdx.x] + woff + (sc - local);
  #pragma unroll
  for (int k=0;k<4;k++){
    int idx = base + t*4 + k;
    if (idx<n){ row_ptr[idx] = run; cursor[idx] = run; run += v[k]; }
  }
}

__global__ void k_prep_pn(const float* __restrict__ pt, float* __restrict__ pnT){
  int r = blockIdx.x;    // 64 prompts
  int l = threadIdx.x;   // 64 lanes
  float2 v = ((const float2*)pt)[r*64 + l];
  float ss = wsumf(v.x*v.x + v.y*v.y);
  float inv = 1.f / fmaxf(sqrtf(ss), 1e-12f);
  pnT[(2*l)*64   + r] = v.x*inv;
  pnT[(2*l+1)*64 + r] = v.y*inv;
}

__global__ void k_scatter(const int* __restrict__ ei, const float* __restrict__ ew,
                          const float* __restrict__ dis, int* cursor,
                          int* __restrict__ csr_col, float* __restrict__ csr_w, int E){
  int i = blockIdx.x*blockDim.x + threadIdx.x;
  int st = gridDim.x*blockDim.x;
  for (int e=i; e<E; e+=st){
    int r = ei[e], c = ei[E+e];
    float w = dis[r]*ew[e]*dis[c];
    int pos = atomicAdd(&cursor[r], 1);
    csr_col[pos] = c; csr_w[pos] = w;
  }
}

// ---------------- fused structural + K ----------------
__global__ __launch_bounds__(256) void k_struct(const float* __restrict__ x,
    const int* __restrict__ row_ptr, const int* __restrict__ csr_col,
    const float* __restrict__ csr_w, const float* __restrict__ pnT_g,
    const float* __restrict__ gamma_p, float* __restrict__ Km, int n){
  __shared__ __align__(16) float pnT[128*64];
  __shared__ __align__(16) float xsrow[4][128];
  for (int i=threadIdx.x; i<128*64; i+=256) pnT[i] = pnT_g[i];
  __syncthreads();
  float g = *gamma_p, om = 1.f - g;
  int lane = threadIdx.x&63, wv = threadIdx.x>>6;
  int wid = blockIdx.x*4 + wv, nw = gridDim.x*4;
  for (int r=wid; r<n; r+=nw){
    int e0 = row_ptr[r], e1 = row_ptr[r+1];
    float ax=0.f, ay=0.f;
    for (int e=e0; e<e1; e++){
      int c = csr_col[e]; float w = csr_w[e];
      float2 xv = ((const float2*)x)[(size_t)c*64 + lane];
      ax = fmaf(w, xv.x, ax); ay = fmaf(w, xv.y, ay);
    }
    float2 xr = ((const float2*)x)[(size_t)r*64 + lane];
    float sx = om*xr.x + g*ax;
    float sy = om*xr.y + g*ay;
    float ss = wsumf(sx*sx + sy*sy);
    float inv = 1.f / fmaxf(sqrtf(ss), 1e-12f);
    xsrow[wv][2*lane]   = sx*inv;
    xsrow[wv][2*lane+1] = sy*inv;
    float acc = 0.f;
    #pragma unroll
    for (int d=0; d<128; d++) acc = fmaf(xsrow[wv][d], pnT[d*64+lane], acc);
    // K = exp(-(1-s)/eps) = 2^((s-1)*10*log2(e))
    Km[(size_t)r*64 + lane] = exp2f((acc - 1.f) * 14.426950408889634f);
  }
}

// ---------------- Sinkhorn ----------------
__global__ __launch_bounds__(256) void k_colsum(const float* __restrict__ Km,
                                                float* __restrict__ kt_out, int n){
  __shared__ float ktsh[64];
  int tid = threadIdx.x;
  if (tid<64) ktsh[tid] = 0.f;
  __syncthreads();
  int lane = tid&63, wv = tid>>6, sub = lane>>4, li = lane&15;
  float4 acc = make_float4(0,0,0,0);
  int wid = blockIdx.x*4 + wv, nw = gridDim.x*4;
  for (int base=wid*4; base<n; base+=nw*4){
    int r = base + sub;
    if (r<n){
      float4 kv = ((const float4*)(Km + (size_t)r*64))[li];
      acc.x += kv.x; acc.y += kv.y; acc.z += kv.z; acc.w += kv.w;
    }
  }
  acc.x += __shfl_xor(acc.x,16); acc.x += __shfl_xor(acc.x,32);
  acc.y += __shfl_xor(acc.y,16); acc.y += __shfl_xor(acc.y,32);
  acc.z += __shfl_xor(acc.z,16); acc.z += __shfl_xor(acc.z,32);
  acc.w += __shfl_xor(acc.w,16); acc.w += __shfl_xor(acc.w,32);
  if (sub==0){
    atomicAdd(&ktsh[li*4+0], acc.x);
    atomicAdd(&ktsh[li*4+1], acc.y);
    atomicAdd(&ktsh[li*4+2], acc.z);
    atomicAdd(&ktsh[li*4+3], acc.w);
  }
  __syncthreads();
  float anorm = 1.0f/(float)n;
  if (tid<64) atomicAdd(&kt_out[tid], ktsh[tid]*anorm);
}

__global__ __launch_bounds__(256) void k_sink(const float* __restrict__ Km,
    const float* __restrict__ kt_in, float* __restrict__ kt_out,
    float* __restrict__ u, int n){
  __shared__ __align__(16) float vsh[64];
  __shared__ float ktsh[64];
  int tid = threadIdx.x;
  if (tid<64){ vsh[tid] = (1.0f/64.0f)/(kt_in[tid] + 1e-30f); ktsh[tid] = 0.f; }
  __syncthreads();
  int lane = tid&63, wv = tid>>6, sub = lane>>4, li = lane&15;
  float4 vv = ((const float4*)vsh)[li];
  float anorm = 1.0f/(float)n;
  float4 acc = make_float4(0,0,0,0);
  int wid = blockIdx.x*4 + wv, nw = gridDim.x*4;
  for (int base=wid*4; base<n; base+=nw*4){
    int r = base + sub;
    float4 kv = make_float4(0,0,0,0);
    if (r<n) kv = ((const float4*)(Km + (size_t)r*64))[li];
    float d = kv.x*vv.x + kv.y*vv.y + kv.z*vv.z + kv.w*vv.w;
    d += __shfl_xor(d,1); d += __shfl_xor(d,2); d += __shfl_xor(d,4); d += __shfl_xor(d,8);
    float un = anorm/(d + 1e-30f);
    if (li==0 && r<n) u[r] = un;
    acc.x = fmaf(kv.x, un, acc.x);
    acc.y = fmaf(kv.y, un, acc.y);
    acc.z = fmaf(kv.z, un, acc.z);
    acc.w = fmaf(kv.w, un, acc.w);
  }
  acc.x += __shfl_xor(acc.x,16); acc.x += __shfl_xor(acc.x,32);
  acc.y += __shfl_xor(acc.y,16); acc.y += __shfl_xor(acc.y,32);
  acc.z += __shfl_xor(acc.z,16); acc.z += __shfl_xor(acc.z,32);
  acc.w += __shfl_xor(acc.w,16); acc.w += __shfl_xor(acc.w,32);
  if (sub==0){
    atomicAdd(&ktsh[li*4+0], acc.x);
    atomicAdd(&ktsh[li*4+1], acc.y);
    atomicAdd(&ktsh[li*4+2], acc.z);
    atomicAdd(&ktsh[li*4+3], acc.w);
  }
  __syncthreads();
  if (tid<64) atomicAdd(&kt_out[tid], ktsh[tid]);
}

// ---------------- final fused: T, loss, message, x_adapted, xf ----------------
__global__ __launch_bounds__(256) void k_final(const float* __restrict__ x,
    const float* __restrict__ Km, const float* __restrict__ u,
    const float* __restrict__ kt19, const float* __restrict__ pt,
    const float* __restrict__ alpha_p, float* __restrict__ out_x,
    float* __restrict__ out_loss, unsigned* __restrict__ xf, int n){
  __shared__ __align__(16) float pts[64*128];
  __shared__ float trow[4][64];
  __shared__ float vsh[64];
  __shared__ float blockloss;
  int tid = threadIdx.x;
  for (int i=tid; i<8192; i+=256) pts[i] = pt[i];
  if (tid<64) vsh[tid] = (1.0f/64.0f)/(kt19[tid] + 1e-30f);
  if (tid==0) blockloss = 0.f;
  __syncthreads();
  float alpha = *alpha_p;
  float coeff = alpha*(float)n;
  int lane = tid&63, wv = tid>>6;
  int wid = blockIdx.x*4 + wv, nw = gridDim.x*4;
  float lossacc = 0.f;
  for (int r=wid; r<n; r+=nw){
    float kv = Km[(size_t)r*64 + lane];
    float T = u[r]*kv*vsh[lane];
    float C = log2f(kv) * (-0.069314718055994531f);   // -eps*ln(K) == 1 - s
    lossacc = fmaf(T, C, lossacc);
    trow[wv][lane] = T;
    float m0=0.f, m1=0.f;
    #pragma unroll
    for (int p=0; p<64; p++){
      float t = trow[wv][p];
      float2 pv = ((const float2*)pts)[p*64 + lane];
      m0 = fmaf(t, pv.x, m0); m1 = fmaf(t, pv.y, m1);
    }
    float2 xr = ((const float2*)x)[(size_t)r*64 + lane];
    float ox = fmaf(coeff, m0, xr.x);
    float oy = fmaf(coeff, m1, xr.y);
    ((float2*)out_x)[(size_t)r*64 + lane] = make_float2(ox, oy);
    float ss = wsumf(ox*ox + oy*oy);
    float inv = 1.f / fmaxf(sqrtf(ss), 1e-12f);
    unsigned lo = f2bf(ox*inv), hi = f2bf(oy*inv);
    xf[(size_t)r*64 + lane] = lo | (hi<<16);
  }
  lossacc = wsumf(lossacc);
  if (lane==0) atomicAdd(&blockloss, lossacc);
  __syncthreads();
  if (tid==0) atomicAdd(out_loss, blockloss);
}

// ---------------- edge scoring ----------------
__global__ __launch_bounds__(256) void k_edge(const int* __restrict__ pte,
    const unsigned* __restrict__ xf, float* __restrict__ wout,
    unsigned* __restrict__ maxw, int ept){
  __shared__ unsigned blockmax;
  if (threadIdx.x==0) blockmax = 0u;
  __syncthreads();
  int lane = threadIdx.x&63, wv = threadIdx.x>>6, sub = lane>>4, li = lane&15;
  int wid = blockIdx.x*4 + wv, nw = gridDim.x*4;
  float lm = 0.f;
  for (int base=wid*4; base<ept; base+=nw*4){
    int e = base + sub;
    float dot = 0.f;
    if (e<ept){
      int r = pte[e], c = pte[ept+e];
      uint4 A = *(((const uint4*)(xf + (size_t)r*64)) + li);
      uint4 B = *(((const uint4*)(xf + (size_t)c*64)) + li);
      dot = dp2(A.x,B.x) + dp2(A.y,B.y) + dp2(A.z,B.z) + dp2(A.w,B.w);
    }
    dot += __shfl_xor(dot,1); dot += __shfl_xor(dot,2);
    dot += __shfl_xor(dot,4); dot += __shfl_xor(dot,8);
    if (li==0 && e<ept){
      float w = fmaxf(dot, 0.f);
      wout[e] = w;
      lm = fmaxf(lm, w);
    }
  }
  #pragma unroll
  for (int d=1; d<64; d<<=1) lm = fmaxf(lm, __shfl_xor(lm, d));
  if (lane==0) atomicMax(&blockmax, __float_as_uint(lm));
  __syncthreads();
  if (threadIdx.x==0) atomicMax(maxw, blockmax);
}

__global__ void k_normw(float* __restrict__ w, const unsigned* __restrict__ maxw, int ept){
  float inv = 1.f/(__uint_as_float(*maxw) + 1e-8f);
  int i = blockIdx.x*blockDim.x + threadIdx.x;
  int st = gridDim.x*blockDim.x;
  for (int e=i; e<ept; e+=st) w[e] *= inv;
}

// ---------------- host ----------------
extern "C" void kernel_launch(void* const* d_in, const int* in_sizes, int n_in,
                              void* d_out, int out_size, void* d_ws, size_t ws_size,
                              hipStream_t stream){
  const float* x       = (const float*)d_in[0];
  const int*   ei      = (const int*)  d_in[1];
  const float* ew      = (const float*)d_in[2];
  const int*   pte     = (const int*)  d_in[3];
  const float* pt      = (const float*)d_in[4];
  const float* alpha_p = (const float*)d_in[5];
  const float* gamma_p = (const float*)d_in[6];
  int n   = in_sizes[0] / D_DIM;
  int E   = in_sizes[1] / 2;
  int ept = in_sizes[3] / 2;

  char* ws = (char*)d_ws;
  int*      cntr    = (int*)     (ws + O_CNTR);
  int*      cntc    = (int*)     (ws + O_CNTC);
  float*    dis     = (float*)   (ws + O_DIS);
  int*      row_ptr = (int*)     (ws + O_ROWPTR);
  int*      cursor  = (int*)     (ws + O_CURSOR);
  int*      part    = (int*)     (ws + O_PART);
  float*    kt      = (float*)   (ws + O_KT);
  unsigned* maxw    = (unsigned*)(ws + O_MAXW);
  float*    pnT     = (float*)   (ws + O_PNT);
  float*    ubuf    = (float*)   (ws + O_U);
  int*      csrc    = (int*)     (ws + O_CSRC);
  float*    csrw    = (float*)   (ws + O_CSRW);
  unsigned* xf      = (unsigned*)(ws + O_XF);
  float*    Km      = (float*)   (ws + O_K);

  float* out_x    = (float*)d_out;
  float* out_loss = (float*)d_out + (size_t)n*D_DIM;
  float* out_w    = out_loss + 1;

  int nb = (n + 1023)/1024;

  k_zero   <<<512, 256, 0, stream>>>(cntr, cntc, kt, maxw, out_loss, n);
  k_deg    <<<2048, 256, 0, stream>>>(ei, E, cntr, cntc);
  k_deginv <<<(n+255)/256, 256, 0, stream>>>(cntc, dis, n);
  k_scan_a <<<nb, 256, 0, stream>>>(cntr, part, n);
  k_scan_b <<<1, 64, 0, stream>>>(part, nb, row_ptr, n, E);
  k_scan_c <<<nb, 256, 0, stream>>>(cntr, part, row_ptr, cursor, n);
  k_prep_pn<<<64, 64, 0, stream>>>(pt, pnT);
  k_scatter<<<2048, 256, 0, stream>>>(ei, ew, dis, cursor, csrc, csrw, E);
  k_struct <<<2048, 256, 0, stream>>>(x, row_ptr, csrc, csrw, pnT, gamma_p, Km, n);
  k_colsum <<<1024, 256, 0, stream>>>(Km, kt, n);
  for (int t=1; t<=20; t++)
    k_sink <<<1024, 256, 0, stream>>>(Km, kt + (t-1)*64, kt + t*64, ubuf, n);
  k_final  <<<2048, 256, 0, stream>>>(x, Km, ubuf, kt + 19*64, pt, alpha_p,
                                      out_x, out_loss, xf, n);
  k_edge   <<<4096, 256, 0, stream>>>(pte, xf, out_w, maxw, ept);
  k_normw  <<<2048, 256, 0, stream>>>(out_w, maxw, ept);
}

// Round 4
// 1942.255 us; speedup vs baseline: 1.1159x; 1.1159x over previous
//
#include <hip/hip_runtime.h>
#include <stdint.h>

#define D_DIM 128
#define P_DIM 64

// ---- workspace layout (bytes) ----
#define O_CNTR   0x000000ull   // N int
#define O_CNTC   0x080000ull   // N int
#define O_DIS    0x100000ull   // N float
#define O_ROWPTR 0x180000ull   // N+1 int
#define O_CURSOR 0x200000ull   // N int
#define O_PART   0x280000ull   // scan partials
#define O_KT     0x290000ull   // 21*64 float
#define O_MAXW   0x2A0000ull   // 1 uint
#define O_PNB    0x2B0000ull   // 64*64 uint (pn transposed, bf16x2 packed)
#define O_U      0x300000ull   // N float
#define O_CSR    0x400000ull   // E uint2 {col, w_bits}  (dead after k_struct)
#define O_XF     0x400000ull   // N*64 uint (bf16x2) -- aliases csr (liveness-disjoint)
#define O_K      0x1C80000ull  // N*64 float

__device__ __forceinline__ float wsumf(float v){
  #pragma unroll
  for (int d=1; d<64; d<<=1) v += __shfl_xor(v, d);
  return v;
}

__device__ __forceinline__ unsigned f2bf(float f){
  unsigned u = __float_as_uint(f);
  return (u + 0x7fffu + ((u>>16)&1u)) >> 16;
}

__device__ __forceinline__ float bflo(unsigned u){ return __uint_as_float(u<<16); }
__device__ __forceinline__ float bfhi(unsigned u){ return __uint_as_float(u & 0xffff0000u); }

__device__ __forceinline__ float dp2(unsigned a, unsigned b){
  return bflo(a)*bflo(b) + bfhi(a)*bfhi(b);
}

// ---------------- setup kernels ----------------
__global__ void k_zero(int* cntr, int* cntc, float* kt, unsigned* maxw, float* loss_slot, int n){
  int i = blockIdx.x*blockDim.x + threadIdx.x;
  int st = gridDim.x*blockDim.x;
  for (int j=i; j<n; j+=st){ cntr[j]=0; cntc[j]=0; }
  for (int j=i; j<21*64; j+=st) kt[j]=0.f;
  if (i==0){ *maxw = 0u; *loss_slot = 0.f; }
}

__global__ void k_deg(const int* __restrict__ ei, int E, int* cntr, int* cntc){
  int i = blockIdx.x*blockDim.x + threadIdx.x;
  int st = gridDim.x*blockDim.x;
  for (int e=i; e<E; e+=st){
    atomicAdd(&cntr[ei[e]], 1);
    atomicAdd(&cntc[ei[E+e]], 1);
  }
}

__global__ void k_deginv(const int* __restrict__ cntc, float* __restrict__ dis, int n){
  int i = blockIdx.x*blockDim.x + threadIdx.x;
  if (i < n){
    int c = cntc[i];
    dis[i] = (c > 0) ? rsqrtf((float)c) : 0.f;
  }
}

__global__ void k_scan_a(const int* __restrict__ cnt, int* __restrict__ part, int n){
  __shared__ int sm[4];
  int base = blockIdx.x*1024;
  int t = threadIdx.x;
  int s = 0;
  #pragma unroll
  for (int k=0;k<4;k++){ int idx = base + t + 256*k; if (idx<n) s += cnt[idx]; }
  #pragma unroll
  for (int d=1; d<64; d<<=1) s += __shfl_xor(s, d);
  if ((t&63)==0) sm[t>>6] = s;
  __syncthreads();
  if (t==0) part[blockIdx.x] = sm[0]+sm[1]+sm[2]+sm[3];
}

__global__ void k_scan_b(int* part, int nb, int* row_ptr, int n, int E){
  if (threadIdx.x==0 && blockIdx.x==0){
    int run = 0;
    for (int i=0;i<nb;i++){ int v = part[i]; part[i] = run; run += v; }
    row_ptr[n] = E;
  }
}

__global__ void k_scan_c(const int* __restrict__ cnt, const int* __restrict__ part,
                         int* __restrict__ row_ptr, int* __restrict__ cursor, int n){
  __shared__ int warp_tot[4];
  int base = blockIdx.x*1024;
  int t = threadIdx.x;
  int lane = t&63, wv = t>>6;
  int v[4];
  #pragma unroll
  for (int k=0;k<4;k++){ int idx = base + t*4 + k; v[k] = (idx<n) ? cnt[idx] : 0; }
  int local = v[0]+v[1]+v[2]+v[3];
  int sc = local;
  #pragma unroll
  for (int d=1; d<64; d<<=1){ int y = __shfl_up(sc, d); if (lane>=d) sc += y; }
  if (lane==63) warp_tot[wv] = sc;
  __syncthreads();
  int woff = 0;
  for (int i=0;i<wv;i++) woff += warp_tot[i];
  int run = part[blockIdx.x] + woff + (sc - local);
  #pragma unroll
  for (int k=0;k<4;k++){
    int idx = base + t*4 + k;
    if (idx<n){ row_ptr[idx] = run; cursor[idx] = run; run += v[k]; }
  }
}

// pnb[k*64 + p] = bf16x2( pn[2k][p], pn[2k+1][p] )   (pn = l2-normalized prompts)
__global__ void k_prep_pn(const float* __restrict__ pt, unsigned* __restrict__ pnb){
  int r = blockIdx.x;    // 64 prompts
  int l = threadIdx.x;   // 64 lanes = d-pair index
  float2 v = ((const float2*)pt)[r*64 + l];
  float ss = wsumf(v.x*v.x + v.y*v.y);
  float inv = 1.f / fmaxf(sqrtf(ss), 1e-12f);
  pnb[l*64 + r] = f2bf(v.x*inv) | (f2bf(v.y*inv) << 16);
}

__global__ void k_scatter(const int* __restrict__ ei, const float* __restrict__ ew,
                          const float* __restrict__ dis, int* cursor,
                          uint2* __restrict__ csr, int E){
  int i = blockIdx.x*blockDim.x + threadIdx.x;
  int st = gridDim.x*blockDim.x;
  for (int e=i; e<E; e+=st){
    int r = ei[e], c = ei[E+e];
    float w = dis[r]*ew[e]*dis[c];
    int pos = atomicAdd(&cursor[r], 1);
    csr[pos] = make_uint2((unsigned)c, __float_as_uint(w));
  }
}

// ---------------- fused structural + K + colsum ----------------
__global__ __launch_bounds__(256) void k_struct(const float* __restrict__ x,
    const int* __restrict__ row_ptr, const uint2* __restrict__ csr,
    const unsigned* __restrict__ pnb_g, const float* __restrict__ gamma_p,
    float* __restrict__ Km, float* __restrict__ kt0, int n){
  __shared__ unsigned pnbs[64*64];           // 16 KB
  __shared__ __align__(16) float xsrow[4][128];
  __shared__ float ktsh[64];
  int tid = threadIdx.x;
  for (int i=tid; i<4096; i+=256) pnbs[i] = pnb_g[i];
  if (tid<64) ktsh[tid] = 0.f;
  __syncthreads();
  float g = *gamma_p, om = 1.f - g;
  int lane = tid&63, wv = tid>>6;
  int wid = blockIdx.x*4 + wv, nw = gridDim.x*4;
  const float2* X2 = (const float2*)x;
  float kacc = 0.f;
  for (int r=wid; r<n; r+=nw){
    int e0 = row_ptr[r], e1 = row_ptr[r+1];
    float ax=0.f, ay=0.f;
    int e = e0;
    for (; e+3 < e1; e += 4){
      uint2 q0 = csr[e], q1 = csr[e+1], q2 = csr[e+2], q3 = csr[e+3];
      float2 v0 = X2[(size_t)q0.x*64 + lane];
      float2 v1 = X2[(size_t)q1.x*64 + lane];
      float2 v2 = X2[(size_t)q2.x*64 + lane];
      float2 v3 = X2[(size_t)q3.x*64 + lane];
      float w0 = __uint_as_float(q0.y), w1 = __uint_as_float(q1.y);
      float w2 = __uint_as_float(q2.y), w3 = __uint_as_float(q3.y);
      ax = fmaf(w0, v0.x, ax); ay = fmaf(w0, v0.y, ay);
      ax = fmaf(w1, v1.x, ax); ay = fmaf(w1, v1.y, ay);
      ax = fmaf(w2, v2.x, ax); ay = fmaf(w2, v2.y, ay);
      ax = fmaf(w3, v3.x, ax); ay = fmaf(w3, v3.y, ay);
    }
    for (; e < e1; e++){
      uint2 q = csr[e];
      float2 xv = X2[(size_t)q.x*64 + lane];
      float w = __uint_as_float(q.y);
      ax = fmaf(w, xv.x, ax); ay = fmaf(w, xv.y, ay);
    }
    float2 xr = X2[(size_t)r*64 + lane];
    float sx = om*xr.x + g*ax;
    float sy = om*xr.y + g*ay;
    float ss = wsumf(sx*sx + sy*sy);
    float inv = 1.f / fmaxf(sqrtf(ss), 1e-12f);
    xsrow[wv][2*lane]   = sx*inv;
    xsrow[wv][2*lane+1] = sy*inv;
    float acc = 0.f;
    #pragma unroll
    for (int k=0; k<64; k++){
      unsigned pp = pnbs[k*64 + lane];
      float2 xv = *(const float2*)&xsrow[wv][2*k];  // wave-uniform broadcast
      acc = fmaf(bflo(pp), xv.x, acc);
      acc = fmaf(bfhi(pp), xv.y, acc);
    }
    // K = exp(-(1-s)/eps) = 2^((s-1)*10*log2(e))
    float kv = exp2f((acc - 1.f) * 14.426950408889634f);
    Km[(size_t)r*64 + lane] = kv;
    kacc += kv;
  }
  atomicAdd(&ktsh[lane], kacc);
  __syncthreads();
  if (tid<64) atomicAdd(&kt0[tid], ktsh[tid] * (1.0f/(float)n));
}

// ---------------- Sinkhorn (XCD-chunked rows) ----------------
__global__ __launch_bounds__(256) void k_sink(const float* __restrict__ Km,
    const float* __restrict__ kt_in, float* __restrict__ kt_out,
    float* __restrict__ u, int n){
  __shared__ __align__(16) float vsh[64];
  __shared__ float ktsh[64];
  int tid = threadIdx.x;
  if (tid<64){ vsh[tid] = (1.0f/64.0f)/(kt_in[tid] + 1e-30f); ktsh[tid] = 0.f; }
  __syncthreads();
  int lane = tid&63, wv = tid>>6, sub = lane>>4, li = lane&15;
  float4 vv = ((const float4*)vsh)[li];
  float anorm = 1.0f/(float)n;
  float4 acc = make_float4(0,0,0,0);
  int xcd = blockIdx.x & 7, lb = blockIdx.x >> 3, nlb = gridDim.x >> 3;
  int r0 = (int)((long long)xcd*n/8), r1 = (int)((long long)(xcd+1)*n/8);
  int wid = lb*4 + wv, nw = nlb*4;
  for (int base=r0+wid*4; base<r1; base+=nw*4){
    int r = base + sub;
    float4 kv = make_float4(0,0,0,0);
    if (r<r1) kv = ((const float4*)(Km + (size_t)r*64))[li];
    float d = kv.x*vv.x + kv.y*vv.y + kv.z*vv.z + kv.w*vv.w;
    d += __shfl_xor(d,1); d += __shfl_xor(d,2); d += __shfl_xor(d,4); d += __shfl_xor(d,8);
    float un = anorm/(d + 1e-30f);
    if (li==0 && r<r1) u[r] = un;
    acc.x = fmaf(kv.x, un, acc.x);
    acc.y = fmaf(kv.y, un, acc.y);
    acc.z = fmaf(kv.z, un, acc.z);
    acc.w = fmaf(kv.w, un, acc.w);
  }
  acc.x += __shfl_xor(acc.x,16); acc.x += __shfl_xor(acc.x,32);
  acc.y += __shfl_xor(acc.y,16); acc.y += __shfl_xor(acc.y,32);
  acc.z += __shfl_xor(acc.z,16); acc.z += __shfl_xor(acc.z,32);
  acc.w += __shfl_xor(acc.w,16); acc.w += __shfl_xor(acc.w,32);
  if (sub==0){
    atomicAdd(&ktsh[li*4+0], acc.x);
    atomicAdd(&ktsh[li*4+1], acc.y);
    atomicAdd(&ktsh[li*4+2], acc.z);
    atomicAdd(&ktsh[li*4+3], acc.w);
  }
  __syncthreads();
  if (tid<64) atomicAdd(&kt_out[tid], ktsh[tid]);
}

// ---------------- final fused: T, loss, message, x_adapted, xf ----------------
__global__ __launch_bounds__(256) void k_final(const float* __restrict__ x,
    const float* __restrict__ Km, const float* __restrict__ u,
    const float* __restrict__ kt19, const float* __restrict__ pt,
    const float* __restrict__ alpha_p, float* __restrict__ out_x,
    float* __restrict__ out_loss, unsigned* __restrict__ xf, int n){
  __shared__ __align__(16) float pts[64*128];
  __shared__ float trow[4][64];
  __shared__ float vsh[64];
  __shared__ float blockloss;
  int tid = threadIdx.x;
  for (int i=tid; i<8192; i+=256) pts[i] = pt[i];
  if (tid<64) vsh[tid] = (1.0f/64.0f)/(kt19[tid] + 1e-30f);
  if (tid==0) blockloss = 0.f;
  __syncthreads();
  float alpha = *alpha_p;
  float coeff = alpha*(float)n;
  int lane = tid&63, wv = tid>>6;
  int xcd = blockIdx.x & 7, lb = blockIdx.x >> 3, nlb = gridDim.x >> 3;
  int r0 = (int)((long long)xcd*n/8), r1 = (int)((long long)(xcd+1)*n/8);
  int wid = lb*4 + wv, nw = nlb*4;
  float lossacc = 0.f;
  for (int r=r0+wid; r<r1; r+=nw){
    float kv = Km[(size_t)r*64 + lane];
    float T = u[r]*kv*vsh[lane];
    float C = log2f(kv) * (-0.069314718055994531f);   // -eps*ln(K) == 1 - s
    lossacc = fmaf(T, C, lossacc);
    trow[wv][lane] = T;
    float m0=0.f, m1=0.f;
    #pragma unroll
    for (int p=0; p<64; p++){
      float t = trow[wv][p];
      float2 pv = ((const float2*)pts)[p*64 + lane];
      m0 = fmaf(t, pv.x, m0); m1 = fmaf(t, pv.y, m1);
    }
    float2 xr = ((const float2*)x)[(size_t)r*64 + lane];
    float ox = fmaf(coeff, m0, xr.x);
    float oy = fmaf(coeff, m1, xr.y);
    ((float2*)out_x)[(size_t)r*64 + lane] = make_float2(ox, oy);
    float ss = wsumf(ox*ox + oy*oy);
    float inv = 1.f / fmaxf(sqrtf(ss), 1e-12f);
    unsigned lo = f2bf(ox*inv), hi = f2bf(oy*inv);
    xf[(size_t)r*64 + lane] = lo | (hi<<16);
  }
  lossacc = wsumf(lossacc);
  if (lane==0) atomicAdd(&blockloss, lossacc);
  __syncthreads();
  if (tid==0) atomicAdd(out_loss, blockloss);
}

// ---------------- edge scoring (2-way unrolled) ----------------
__global__ __launch_bounds__(256) void k_edge(const int* __restrict__ pte,
    const unsigned* __restrict__ xf, float* __restrict__ wout,
    unsigned* __restrict__ maxw, int ept){
  __shared__ unsigned blockmax;
  if (threadIdx.x==0) blockmax = 0u;
  __syncthreads();
  int lane = threadIdx.x&63, wv = threadIdx.x>>6, sub = lane>>4, li = lane&15;
  int wid = blockIdx.x*4 + wv, nw = gridDim.x*4;
  float lm = 0.f;
  for (int base=wid*8; base<ept; base+=nw*8){
    int eA = base + sub, eB = base + 4 + sub;
    bool vA = eA < ept, vB = eB < ept;
    float dA = 0.f, dB = 0.f;
    uint4 A0, A1, B0, B1;
    int rA=0,cA=0,rB=0,cB=0;
    if (vA){ rA = pte[eA]; cA = pte[ept+eA]; }
    if (vB){ rB = pte[eB]; cB = pte[ept+eB]; }
    if (vA){
      A0 = *(((const uint4*)(xf + (size_t)rA*64)) + li);
      A1 = *(((const uint4*)(xf + (size_t)cA*64)) + li);
    }
    if (vB){
      B0 = *(((const uint4*)(xf + (size_t)rB*64)) + li);
      B1 = *(((const uint4*)(xf + (size_t)cB*64)) + li);
    }
    if (vA) dA = dp2(A0.x,A1.x) + dp2(A0.y,A1.y) + dp2(A0.z,A1.z) + dp2(A0.w,A1.w);
    if (vB) dB = dp2(B0.x,B1.x) + dp2(B0.y,B1.y) + dp2(B0.z,B1.z) + dp2(B0.w,B1.w);
    dA += __shfl_xor(dA,1); dB += __shfl_xor(dB,1);
    dA += __shfl_xor(dA,2); dB += __shfl_xor(dB,2);
    dA += __shfl_xor(dA,4); dB += __shfl_xor(dB,4);
    dA += __shfl_xor(dA,8); dB += __shfl_xor(dB,8);
    if (li==0){
      if (vA){ float w = fmaxf(dA, 0.f); wout[eA] = w; lm = fmaxf(lm, w); }
      if (vB){ float w = fmaxf(dB, 0.f); wout[eB] = w; lm = fmaxf(lm, w); }
    }
  }
  #pragma unroll
  for (int d=1; d<64; d<<=1) lm = fmaxf(lm, __shfl_xor(lm, d));
  if (lane==0) atomicMax(&blockmax, __float_as_uint(lm));
  __syncthreads();
  if (threadIdx.x==0) atomicMax(maxw, blockmax);
}

__global__ void k_normw(float* __restrict__ w, const unsigned* __restrict__ maxw, int ept){
  float inv = 1.f/(__uint_as_float(*maxw) + 1e-8f);
  int i = blockIdx.x*blockDim.x + threadIdx.x;
  int st = gridDim.x*blockDim.x;
  for (int e=i; e<ept; e+=st) w[e] *= inv;
}

// ---------------- host ----------------
extern "C" void kernel_launch(void* const* d_in, const int* in_sizes, int n_in,
                              void* d_out, int out_size, void* d_ws, size_t ws_size,
                              hipStream_t stream){
  const float* x       = (const float*)d_in[0];
  const int*   ei      = (const int*)  d_in[1];
  const float* ew      = (const float*)d_in[2];
  const int*   pte     = (const int*)  d_in[3];
  const float* pt      = (const float*)d_in[4];
  const float* alpha_p = (const float*)d_in[5];
  const float* gamma_p = (const float*)d_in[6];
  int n   = in_sizes[0] / D_DIM;
  int E   = in_sizes[1] / 2;
  int ept = in_sizes[3] / 2;

  char* ws = (char*)d_ws;
  int*      cntr    = (int*)     (ws + O_CNTR);
  int*      cntc    = (int*)     (ws + O_CNTC);
  float*    dis     = (float*)   (ws + O_DIS);
  int*      row_ptr = (int*)     (ws + O_ROWPTR);
  int*      cursor  = (int*)     (ws + O_CURSOR);
  int*      part    = (int*)     (ws + O_PART);
  float*    kt      = (float*)   (ws + O_KT);
  unsigned* maxw    = (unsigned*)(ws + O_MAXW);
  unsigned* pnb     = (unsigned*)(ws + O_PNB);
  float*    ubuf    = (float*)   (ws + O_U);
  uint2*    csr     = (uint2*)   (ws + O_CSR);
  unsigned* xf      = (unsigned*)(ws + O_XF);
  float*    Km      = (float*)   (ws + O_K);

  float* out_x    = (float*)d_out;
  float* out_loss = (float*)d_out + (size_t)n*D_DIM;
  float* out_w    = out_loss + 1;

  int nb = (n + 1023)/1024;

  k_zero   <<<512, 256, 0, stream>>>(cntr, cntc, kt, maxw, out_loss, n);
  k_deg    <<<2048, 256, 0, stream>>>(ei, E, cntr, cntc);
  k_deginv <<<(n+255)/256, 256, 0, stream>>>(cntc, dis, n);
  k_scan_a <<<nb, 256, 0, stream>>>(cntr, part, n);
  k_scan_b <<<1, 64, 0, stream>>>(part, nb, row_ptr, n, E);
  k_scan_c <<<nb, 256, 0, stream>>>(cntr, part, row_ptr, cursor, n);
  k_prep_pn<<<64, 64, 0, stream>>>(pt, pnb);
  k_scatter<<<2048, 256, 0, stream>>>(ei, ew, dis, cursor, csr, E);
  k_struct <<<2048, 256, 0, stream>>>(x, row_ptr, csr, pnb, gamma_p, Km, kt, n);
  for (int t=1; t<=20; t++)
    k_sink <<<1024, 256, 0, stream>>>(Km, kt + (t-1)*64, kt + t*64, ubuf, n);
  k_final  <<<2048, 256, 0, stream>>>(x, Km, ubuf, kt + 19*64, pt, alpha_p,
                                      out_x, out_loss, xf, n);
  k_edge   <<<4096, 256, 0, stream>>>(pte, xf, out_w, maxw, ept);
  k_normw  <<<2048, 256, 0, stream>>>(out_w, maxw, ept);
}

// Round 6
// 1851.140 us; speedup vs baseline: 1.1708x; 1.0492x over previous
//
#include <hip/hip_runtime.h>
#include <stdint.h>

#define D_DIM 128
#define P_DIM 64

// ---- workspace layout (bytes) ----
#define O_CNTR   0x000000ull   // N int
#define O_CNTC   0x080000ull   // N int
#define O_DIS    0x100000ull   // N float
#define O_ROWPTR 0x180000ull   // N+1 int
#define O_CURSOR 0x200000ull   // N int
#define O_PART   0x280000ull   // scan partials
#define O_KT     0x290000ull   // 21*64 float
#define O_MAXW   0x2A0000ull   // 1 uint
#define O_PNB    0x2B0000ull   // 64*64 uint (pn transposed, bf16x2 packed)
#define O_U      0x300000ull   // N float
#define O_CSR    0x400000ull   // E uint2 {col, w_bits}  (dead after k_struct)
#define O_XF     0x400000ull   // N*64 uint (bf16x2) -- aliases csr (liveness-disjoint)
#define O_K      0x1C80000ull  // N*64 float
#define O_XB     0x3580000ull  // N*64 uint (x rows, bf16x2 packed)

__device__ __forceinline__ float wsumf(float v){
  #pragma unroll
  for (int d=1; d<64; d<<=1) v += __shfl_xor(v, d);
  return v;
}

__device__ __forceinline__ unsigned f2bf(float f){
  unsigned u = __float_as_uint(f);
  return (u + 0x7fffu + ((u>>16)&1u)) >> 16;
}

__device__ __forceinline__ float bflo(unsigned u){ return __uint_as_float(u<<16); }
__device__ __forceinline__ float bfhi(unsigned u){ return __uint_as_float(u & 0xffff0000u); }

__device__ __forceinline__ float dp2(unsigned a, unsigned b){
  return bflo(a)*bflo(b) + bfhi(a)*bfhi(b);
}

// ---------------- setup kernels ----------------
__global__ void k_zero(int* cntr, int* cntc, float* kt, unsigned* maxw, float* loss_slot, int n){
  int i = blockIdx.x*blockDim.x + threadIdx.x;
  int st = gridDim.x*blockDim.x;
  for (int j=i; j<n; j+=st){ cntr[j]=0; cntc[j]=0; }
  for (int j=i; j<21*64; j+=st) kt[j]=0.f;
  if (i==0){ *maxw = 0u; *loss_slot = 0.f; }
}

__global__ void k_deg(const int* __restrict__ ei, int E, int* cntr, int* cntc){
  int i = blockIdx.x*blockDim.x + threadIdx.x;
  int st = gridDim.x*blockDim.x;
  for (int e=i; e<E; e+=st){
    atomicAdd(&cntr[ei[e]], 1);
    atomicAdd(&cntc[ei[E+e]], 1);
  }
}

__global__ void k_deginv(const int* __restrict__ cntc, float* __restrict__ dis, int n){
  int i = blockIdx.x*blockDim.x + threadIdx.x;
  if (i < n){
    int c = cntc[i];
    dis[i] = (c > 0) ? rsqrtf((float)c) : 0.f;
  }
}

// pack x rows to bf16x2 (streaming)
__global__ void k_prep_x(const float* __restrict__ x, unsigned* __restrict__ xb, int n64){
  int i = blockIdx.x*blockDim.x + threadIdx.x;
  int st = gridDim.x*blockDim.x;
  for (int j=i; j<n64; j+=st){
    float2 v = ((const float2*)x)[j];
    xb[j] = f2bf(v.x) | (f2bf(v.y)<<16);
  }
}

__global__ void k_scan_a(const int* __restrict__ cnt, int* __restrict__ part, int n){
  __shared__ int sm[4];
  int base = blockIdx.x*1024;
  int t = threadIdx.x;
  int s = 0;
  #pragma unroll
  for (int k=0;k<4;k++){ int idx = base + t + 256*k; if (idx<n) s += cnt[idx]; }
  #pragma unroll
  for (int d=1; d<64; d<<=1) s += __shfl_xor(s, d);
  if ((t&63)==0) sm[t>>6] = s;
  __syncthreads();
  if (t==0) part[blockIdx.x] = sm[0]+sm[1]+sm[2]+sm[3];
}

__global__ void k_scan_b(int* part, int nb, int* row_ptr, int n, int E){
  if (threadIdx.x==0 && blockIdx.x==0){
    int run = 0;
    for (int i=0;i<nb;i++){ int v = part[i]; part[i] = run; run += v; }
    row_ptr[n] = E;
  }
}

__global__ void k_scan_c(const int* __restrict__ cnt, const int* __restrict__ part,
                         int* __restrict__ row_ptr, int* __restrict__ cursor, int n){
  __shared__ int warp_tot[4];
  int base = blockIdx.x*1024;
  int t = threadIdx.x;
  int lane = t&63, wv = t>>6;
  int v[4];
  #pragma unroll
  for (int k=0;k<4;k++){ int idx = base + t*4 + k; v[k] = (idx<n) ? cnt[idx] : 0; }
  int local = v[0]+v[1]+v[2]+v[3];
  int sc = local;
  #pragma unroll
  for (int d=1; d<64; d<<=1){ int y = __shfl_up(sc, d); if (lane>=d) sc += y; }
  if (lane==63) warp_tot[wv] = sc;
  __syncthreads();
  int woff = 0;
  for (int i=0;i<wv;i++) woff += warp_tot[i];
  int run = part[blockIdx.x] + woff + (sc - local);
  #pragma unroll
  for (int k=0;k<4;k++){
    int idx = base + t*4 + k;
    if (idx<n){ row_ptr[idx] = run; cursor[idx] = run; run += v[k]; }
  }
}

// pnb[k*64 + p] = bf16x2( pn[2k][p], pn[2k+1][p] )   (pn = l2-normalized prompts)
__global__ void k_prep_pn(const float* __restrict__ pt, unsigned* __restrict__ pnb){
  int r = blockIdx.x;    // 64 prompts
  int l = threadIdx.x;   // 64 lanes = d-pair index
  float2 v = ((const float2*)pt)[r*64 + l];
  float ss = wsumf(v.x*v.x + v.y*v.y);
  float inv = 1.f / fmaxf(sqrtf(ss), 1e-12f);
  pnb[l*64 + r] = f2bf(v.x*inv) | (f2bf(v.y*inv) << 16);
}

__global__ void k_scatter(const int* __restrict__ ei, const float* __restrict__ ew,
                          const float* __restrict__ dis, int* cursor,
                          uint2* __restrict__ csr, int E){
  int i = blockIdx.x*blockDim.x + threadIdx.x;
  int st = gridDim.x*blockDim.x;
  for (int e=i; e<E; e+=st){
    int r = ei[e], c = ei[E+e];
    float w = dis[r]*ew[e]*dis[c];
    int pos = atomicAdd(&cursor[r], 1);
    csr[pos] = make_uint2((unsigned)c, __float_as_uint(w));
  }
}

// ---------------- fused structural + K + colsum ----------------
__global__ __launch_bounds__(256) void k_struct(const float* __restrict__ x,
    const unsigned* __restrict__ xb,
    const int* __restrict__ row_ptr, const uint2* __restrict__ csr,
    const unsigned* __restrict__ pnb_g, const float* __restrict__ gamma_p,
    float* __restrict__ Km, float* __restrict__ kt0, int n){
  __shared__ unsigned pnbs[64*64];           // 16 KB
  __shared__ __align__(16) float xsrow[4][128];
  __shared__ float ktsh[64];
  int tid = threadIdx.x;
  for (int i=tid; i<4096; i+=256) pnbs[i] = pnb_g[i];
  if (tid<64) ktsh[tid] = 0.f;
  __syncthreads();
  float g = *gamma_p, om = 1.f - g;
  int lane = tid&63, wv = tid>>6;
  int wid = blockIdx.x*4 + wv, nw = gridDim.x*4;
  const float2* X2 = (const float2*)x;
  float kacc = 0.f;
  for (int r=wid; r<n; r+=nw){
    int e0 = row_ptr[r], e1 = row_ptr[r+1];
    float ax=0.f, ay=0.f;
    int e = e0;
    for (; e+7 < e1; e += 8){
      uint2 q0 = csr[e],   q1 = csr[e+1], q2 = csr[e+2], q3 = csr[e+3];
      uint2 q4 = csr[e+4], q5 = csr[e+5], q6 = csr[e+6], q7 = csr[e+7];
      unsigned b0 = xb[(size_t)q0.x*64 + lane];
      unsigned b1 = xb[(size_t)q1.x*64 + lane];
      unsigned b2 = xb[(size_t)q2.x*64 + lane];
      unsigned b3 = xb[(size_t)q3.x*64 + lane];
      unsigned b4 = xb[(size_t)q4.x*64 + lane];
      unsigned b5 = xb[(size_t)q5.x*64 + lane];
      unsigned b6 = xb[(size_t)q6.x*64 + lane];
      unsigned b7 = xb[(size_t)q7.x*64 + lane];
      float w0 = __uint_as_float(q0.y), w1 = __uint_as_float(q1.y);
      float w2 = __uint_as_float(q2.y), w3 = __uint_as_float(q3.y);
      float w4 = __uint_as_float(q4.y), w5 = __uint_as_float(q5.y);
      float w6 = __uint_as_float(q6.y), w7 = __uint_as_float(q7.y);
      ax = fmaf(w0, bflo(b0), ax); ay = fmaf(w0, bfhi(b0), ay);
      ax = fmaf(w1, bflo(b1), ax); ay = fmaf(w1, bfhi(b1), ay);
      ax = fmaf(w2, bflo(b2), ax); ay = fmaf(w2, bfhi(b2), ay);
      ax = fmaf(w3, bflo(b3), ax); ay = fmaf(w3, bfhi(b3), ay);
      ax = fmaf(w4, bflo(b4), ax); ay = fmaf(w4, bfhi(b4), ay);
      ax = fmaf(w5, bflo(b5), ax); ay = fmaf(w5, bfhi(b5), ay);
      ax = fmaf(w6, bflo(b6), ax); ay = fmaf(w6, bfhi(b6), ay);
      ax = fmaf(w7, bflo(b7), ax); ay = fmaf(w7, bfhi(b7), ay);
    }
    for (; e < e1; e++){
      uint2 q = csr[e];
      unsigned b = xb[(size_t)q.x*64 + lane];
      float w = __uint_as_float(q.y);
      ax = fmaf(w, bflo(b), ax); ay = fmaf(w, bfhi(b), ay);
    }
    float2 xr = X2[(size_t)r*64 + lane];
    float sx = om*xr.x + g*ax;
    float sy = om*xr.y + g*ay;
    float ss = wsumf(sx*sx + sy*sy);
    float inv = 1.f / fmaxf(sqrtf(ss), 1e-12f);
    xsrow[wv][2*lane]   = sx*inv;
    xsrow[wv][2*lane+1] = sy*inv;
    float acc = 0.f;
    #pragma unroll
    for (int k=0; k<64; k++){
      unsigned pp = pnbs[k*64 + lane];
      float2 xv = *(const float2*)&xsrow[wv][2*k];  // wave-uniform broadcast
      acc = fmaf(bflo(pp), xv.x, acc);
      acc = fmaf(bfhi(pp), xv.y, acc);
    }
    // K = exp(-(1-s)/eps) = 2^((s-1)*10*log2(e))
    float kv = exp2f((acc - 1.f) * 14.426950408889634f);
    Km[(size_t)r*64 + lane] = kv;
    kacc += kv;
  }
  atomicAdd(&ktsh[lane], kacc);
  __syncthreads();
  if (tid<64) atomicAdd(&kt0[tid], ktsh[tid] * (1.0f/(float)n));
}

// ---------------- Sinkhorn (XCD-chunked rows) ----------------
__global__ __launch_bounds__(256) void k_sink(const float* __restrict__ Km,
    const float* __restrict__ kt_in, float* __restrict__ kt_out,
    float* __restrict__ u, int n){
  __shared__ __align__(16) float vsh[64];
  __shared__ float ktsh[64];
  int tid = threadIdx.x;
  if (tid<64){ vsh[tid] = (1.0f/64.0f)/(kt_in[tid] + 1e-30f); ktsh[tid] = 0.f; }
  __syncthreads();
  int lane = tid&63, wv = tid>>6, sub = lane>>4, li = lane&15;
  float4 vv = ((const float4*)vsh)[li];
  float anorm = 1.0f/(float)n;
  float4 acc = make_float4(0,0,0,0);
  int xcd = blockIdx.x & 7, lb = blockIdx.x >> 3, nlb = gridDim.x >> 3;
  int r0 = (int)((long long)xcd*n/8), r1 = (int)((long long)(xcd+1)*n/8);
  int wid = lb*4 + wv, nw = nlb*4;
  for (int base=r0+wid*4; base<r1; base+=nw*4){
    int r = base + sub;
    float4 kv = make_float4(0,0,0,0);
    if (r<r1) kv = ((const float4*)(Km + (size_t)r*64))[li];
    float d = kv.x*vv.x + kv.y*vv.y + kv.z*vv.z + kv.w*vv.w;
    d += __shfl_xor(d,1); d += __shfl_xor(d,2); d += __shfl_xor(d,4); d += __shfl_xor(d,8);
    float un = anorm/(d + 1e-30f);
    if (li==0 && r<r1) u[r] = un;
    acc.x = fmaf(kv.x, un, acc.x);
    acc.y = fmaf(kv.y, un, acc.y);
    acc.z = fmaf(kv.z, un, acc.z);
    acc.w = fmaf(kv.w, un, acc.w);
  }
  acc.x += __shfl_xor(acc.x,16); acc.x += __shfl_xor(acc.x,32);
  acc.y += __shfl_xor(acc.y,16); acc.y += __shfl_xor(acc.y,32);
  acc.z += __shfl_xor(acc.z,16); acc.z += __shfl_xor(acc.z,32);
  acc.w += __shfl_xor(acc.w,16); acc.w += __shfl_xor(acc.w,32);
  if (sub==0){
    atomicAdd(&ktsh[li*4+0], acc.x);
    atomicAdd(&ktsh[li*4+1], acc.y);
    atomicAdd(&ktsh[li*4+2], acc.z);
    atomicAdd(&ktsh[li*4+3], acc.w);
  }
  __syncthreads();
  if (tid<64) atomicAdd(&kt_out[tid], ktsh[tid]);
}

// ---------------- final fused: T, loss, message, x_adapted, xf ----------------
__global__ __launch_bounds__(256) void k_final(const float* __restrict__ x,
    const float* __restrict__ Km, const float* __restrict__ u,
    const float* __restrict__ kt19, const float* __restrict__ pt,
    const float* __restrict__ alpha_p, float* __restrict__ out_x,
    float* __restrict__ out_loss, unsigned* __restrict__ xf, int n){
  __shared__ __align__(16) float pts[64*128];
  __shared__ float trow[4][64];
  __shared__ float vsh[64];
  __shared__ float blockloss;
  int tid = threadIdx.x;
  for (int i=tid; i<8192; i+=256) pts[i] = pt[i];
  if (tid<64) vsh[tid] = (1.0f/64.0f)/(kt19[tid] + 1e-30f);
  if (tid==0) blockloss = 0.f;
  __syncthreads();
  float alpha = *alpha_p;
  float coeff = alpha*(float)n;
  int lane = tid&63, wv = tid>>6;
  int xcd = blockIdx.x & 7, lb = blockIdx.x >> 3, nlb = gridDim.x >> 3;
  int r0 = (int)((long long)xcd*n/8), r1 = (int)((long long)(xcd+1)*n/8);
  int wid = lb*4 + wv, nw = nlb*4;
  float lossacc = 0.f;
  for (int r=r0+wid; r<r1; r+=nw){
    float kv = Km[(size_t)r*64 + lane];
    float T = u[r]*kv*vsh[lane];
    float C = log2f(kv) * (-0.069314718055994531f);   // -eps*ln(K) == 1 - s
    lossacc = fmaf(T, C, lossacc);
    trow[wv][lane] = T;
    float m0=0.f, m1=0.f;
    #pragma unroll
    for (int p=0; p<64; p++){
      float t = trow[wv][p];
      float2 pv = ((const float2*)pts)[p*64 + lane];
      m0 = fmaf(t, pv.x, m0); m1 = fmaf(t, pv.y, m1);
    }
    float2 xr = ((const float2*)x)[(size_t)r*64 + lane];
    float ox = fmaf(coeff, m0, xr.x);
    float oy = fmaf(coeff, m1, xr.y);
    ((float2*)out_x)[(size_t)r*64 + lane] = make_float2(ox, oy);
    float ss = wsumf(ox*ox + oy*oy);
    float inv = 1.f / fmaxf(sqrtf(ss), 1e-12f);
    unsigned lo = f2bf(ox*inv), hi = f2bf(oy*inv);
    xf[(size_t)r*64 + lane] = lo | (hi<<16);
  }
  lossacc = wsumf(lossacc);
  if (lane==0) atomicAdd(&blockloss, lossacc);
  __syncthreads();
  if (tid==0) atomicAdd(out_loss, blockloss);
}

// ---------------- edge scoring (4-way unrolled) ----------------
__global__ __launch_bounds__(256) void k_edge(const int* __restrict__ pte,
    const unsigned* __restrict__ xf, float* __restrict__ wout,
    unsigned* __restrict__ maxw, int ept){
  __shared__ unsigned blockmax;
  if (threadIdx.x==0) blockmax = 0u;
  __syncthreads();
  int lane = threadIdx.x&63, wv = threadIdx.x>>6, sub = lane>>4, li = lane&15;
  int wid = blockIdx.x*4 + wv, nw = gridDim.x*4;
  float lm = 0.f;
  for (int base=wid*16; base<ept; base+=nw*16){
    int ej[4]; bool vj[4]; int rj[4], cj[4];
    uint4 Aj[4], Bj[4];
    float dj[4];
    #pragma unroll
    for (int j=0;j<4;j++){ ej[j] = base + 4*j + sub; vj[j] = ej[j] < ept; }
    #pragma unroll
    for (int j=0;j<4;j++){
      rj[j] = vj[j] ? pte[ej[j]] : 0;
      cj[j] = vj[j] ? pte[ept+ej[j]] : 0;
    }
    #pragma unroll
    for (int j=0;j<4;j++){
      Aj[j] = *(((const uint4*)(xf + (size_t)rj[j]*64)) + li);
      Bj[j] = *(((const uint4*)(xf + (size_t)cj[j]*64)) + li);
    }
    #pragma unroll
    for (int j=0;j<4;j++){
      dj[j] = dp2(Aj[j].x,Bj[j].x) + dp2(Aj[j].y,Bj[j].y)
            + dp2(Aj[j].z,Bj[j].z) + dp2(Aj[j].w,Bj[j].w);
      dj[j] += __shfl_xor(dj[j],1); dj[j] += __shfl_xor(dj[j],2);
      dj[j] += __shfl_xor(dj[j],4); dj[j] += __shfl_xor(dj[j],8);
    }
    if (li==0){
      #pragma unroll
      for (int j=0;j<4;j++){
        if (vj[j]){ float w = fmaxf(dj[j], 0.f); wout[ej[j]] = w; lm = fmaxf(lm, w); }
      }
    }
  }
  #pragma unroll
  for (int d=1; d<64; d<<=1) lm = fmaxf(lm, __shfl_xor(lm, d));
  if (lane==0) atomicMax(&blockmax, __float_as_uint(lm));
  __syncthreads();
  if (threadIdx.x==0) atomicMax(maxw, blockmax);
}

__global__ void k_normw(float* __restrict__ w, const unsigned* __restrict__ maxw, int ept){
  float inv = 1.f/(__uint_as_float(*maxw) + 1e-8f);
  int i = blockIdx.x*blockDim.x + threadIdx.x;
  int st = gridDim.x*blockDim.x;
  for (int e=i; e<ept; e+=st) w[e] *= inv;
}

// ---------------- host ----------------
extern "C" void kernel_launch(void* const* d_in, const int* in_sizes, int n_in,
                              void* d_out, int out_size, void* d_ws, size_t ws_size,
                              hipStream_t stream){
  const float* x       = (const float*)d_in[0];
  const int*   ei      = (const int*)  d_in[1];
  const float* ew      = (const float*)d_in[2];
  const int*   pte     = (const int*)  d_in[3];
  const float* pt      = (const float*)d_in[4];
  const float* alpha_p = (const float*)d_in[5];
  const float* gamma_p = (const float*)d_in[6];
  int n   = in_sizes[0] / D_DIM;
  int E   = in_sizes[1] / 2;
  int ept = in_sizes[3] / 2;

  char* ws = (char*)d_ws;
  int*      cntr    = (int*)     (ws + O_CNTR);
  int*      cntc    = (int*)     (ws + O_CNTC);
  float*    dis     = (float*)   (ws + O_DIS);
  int*      row_ptr = (int*)     (ws + O_ROWPTR);
  int*      cursor  = (int*)     (ws + O_CURSOR);
  int*      part    = (int*)     (ws + O_PART);
  float*    kt      = (float*)   (ws + O_KT);
  unsigned* maxw    = (unsigned*)(ws + O_MAXW);
  unsigned* pnb     = (unsigned*)(ws + O_PNB);
  float*    ubuf    = (float*)   (ws + O_U);
  uint2*    csr     = (uint2*)   (ws + O_CSR);
  unsigned* xf      = (unsigned*)(ws + O_XF);
  float*    Km      = (float*)   (ws + O_K);
  unsigned* xb      = (unsigned*)(ws + O_XB);

  float* out_x    = (float*)d_out;
  float* out_loss = (float*)d_out + (size_t)n*D_DIM;
  float* out_w    = out_loss + 1;

  int nb = (n + 1023)/1024;

  k_zero   <<<512, 256, 0, stream>>>(cntr, cntc, kt, maxw, out_loss, n);
  k_deg    <<<2048, 256, 0, stream>>>(ei, E, cntr, cntc);
  k_deginv <<<(n+255)/256, 256, 0, stream>>>(cntc, dis, n);
  k_prep_x <<<2048, 256, 0, stream>>>(x, xb, n*64);
  k_scan_a <<<nb, 256, 0, stream>>>(cntr, part, n);
  k_scan_b <<<1, 64, 0, stream>>>(part, nb, row_ptr, n, E);
  k_scan_c <<<nb, 256, 0, stream>>>(cntr, part, row_ptr, cursor, n);
  k_prep_pn<<<64, 64, 0, stream>>>(pt, pnb);
  k_scatter<<<2048, 256, 0, stream>>>(ei, ew, dis, cursor, csr, E);
  k_struct <<<1024, 256, 0, stream>>>(x, xb, row_ptr, csr, pnb, gamma_p, Km, kt, n);
  for (int t=1; t<=20; t++)
    k_sink <<<1024, 256, 0, stream>>>(Km, kt + (t-1)*64, kt + t*64, ubuf, n);
  k_final  <<<1024, 256, 0, stream>>>(x, Km, ubuf, kt + 19*64, pt, alpha_p,
                                      out_x, out_loss, xf, n);
  k_edge   <<<2048, 256, 0, stream>>>(pte, xf, out_w, maxw, ept);
  k_normw  <<<2048, 256, 0, stream>>>(out_w, maxw, ept);
}